// Round 1
// baseline (918.372 us; speedup 1.0000x reference)
//
#include <hip/hip_runtime.h>
#include <hip/hip_bf16.h>
#include <math.h>

#define N_NODES 50000
#define NFEAT 256
#define NHID 64
#define NHEADS 8
#define FTOT 512
#define E_TOT 1650000
#define ALPHA 0.2f

__device__ __forceinline__ float bflo(unsigned u) {
  union { unsigned u32; float f; } c; c.u32 = u << 16; return c.f;
}
__device__ __forceinline__ float bfhi(unsigned u) {
  union { unsigned u32; float f; } c; c.u32 = u & 0xffff0000u; return c.f;
}

// h1[n, head*64+j] = sum_k x[n,k] * W[head,k,j]   (fp32 accum, bf16 out)
__global__ __launch_bounds__(256) void gemm_kernel(
    const float* __restrict__ x, const float* __restrict__ W,
    __hip_bfloat16* __restrict__ h1) {
  __shared__ float As[16][65];   // [kk][m], padded vs 16-way store conflict
  __shared__ float Bs[16][64];   // [kk][c]
  int bm = blockIdx.x * 64;
  int head = blockIdx.y;
  const float* Wh = W + (size_t)head * NFEAT * NHID;
  int tid = threadIdx.x;
  int tr = tid >> 4, tc = tid & 15;
  float acc[4][4] = {};
  for (int k0 = 0; k0 < NFEAT; k0 += 16) {
#pragma unroll
    for (int i = 0; i < 4; ++i) {
      int idx = tid + i * 256;
      int r = idx >> 4, kk = idx & 15;
      int gr = bm + r;
      As[kk][r] = (gr < N_NODES) ? x[(size_t)gr * NFEAT + k0 + kk] : 0.f;
    }
#pragma unroll
    for (int i = 0; i < 4; ++i) {
      int idx = tid + i * 256;
      int kk = idx >> 6, c = idx & 63;
      Bs[kk][c] = Wh[(size_t)(k0 + kk) * NHID + c];
    }
    __syncthreads();
#pragma unroll
    for (int kk = 0; kk < 16; ++kk) {
      float a[4], b[4];
#pragma unroll
      for (int i = 0; i < 4; ++i) a[i] = As[kk][tr * 4 + i];
#pragma unroll
      for (int j = 0; j < 4; ++j) b[j] = Bs[kk][tc * 4 + j];
#pragma unroll
      for (int i = 0; i < 4; ++i)
#pragma unroll
        for (int j = 0; j < 4; ++j) acc[i][j] += a[i] * b[j];
    }
    __syncthreads();
  }
#pragma unroll
  for (int i = 0; i < 4; ++i) {
    int row = bm + tr * 4 + i;
    if (row < N_NODES) {
      size_t base = (size_t)row * FTOT + head * 64 + tc * 4;
#pragma unroll
      for (int j = 0; j < 4; j += 2) {
        __hip_bfloat162 pr;
        pr.x = __float2bfloat16(acc[i][j]);
        pr.y = __float2bfloat16(acc[i][j + 1]);
        *reinterpret_cast<__hip_bfloat162*>(h1 + base + j) = pr;
      }
    }
  }
}

// f1[n,h] = sum_j h1[n,h*64+j]*a[h,j];  f2 with a[h,64+j].  4 nodes/block.
__global__ __launch_bounds__(256) void f1f2_kernel(
    const __hip_bfloat16* __restrict__ h1, const float* __restrict__ a,
    float* __restrict__ f1, float* __restrict__ f2) {
  int n = blockIdx.x * 4 + (threadIdx.x >> 6);
  int l = threadIdx.x & 63;
  float s1[8], s2[8];
#pragma unroll
  for (int i = 0; i < 8; ++i) {
    float h = __bfloat162float(h1[(size_t)n * FTOT + i * 64 + l]);
    s1[i] = h * a[i * 128 + l];
    s2[i] = h * a[i * 128 + 64 + l];
  }
#pragma unroll
  for (int o = 1; o < 64; o <<= 1) {
#pragma unroll
    for (int i = 0; i < 8; ++i) {
      s1[i] += __shfl_xor(s1[i], o);
      s2[i] += __shfl_xor(s2[i], o);
    }
  }
  if (l == 0) {
#pragma unroll
    for (int i = 0; i < 8; ++i) {
      f1[n * 8 + i] = s1[i];
      f2[n * 8 + i] = s2[i];
    }
  }
}

__global__ __launch_bounds__(256) void hist_kernel(const int* __restrict__ src,
                                                   int* __restrict__ cnt) {
  int i = blockIdx.x * 256 + threadIdx.x;
  if (i < E_TOT) atomicAdd(&cnt[src[i]], 1);
}

// exclusive prefix sum of cnt[50000] -> offsets[50001], single block of 1024
__global__ __launch_bounds__(1024) void scan_kernel(const int* __restrict__ cnt,
                                                    int* __restrict__ offsets) {
  __shared__ int sh[1024];
  __shared__ int carry;
  int tid = threadIdx.x;
  if (tid == 0) carry = 0;
  __syncthreads();
  for (int base = 0; base < N_NODES; base += 1024) {
    int i = base + tid;
    int v = (i < N_NODES) ? cnt[i] : 0;
    sh[tid] = v;
    __syncthreads();
    for (int off = 1; off < 1024; off <<= 1) {
      int t = (tid >= off) ? sh[tid - off] : 0;
      __syncthreads();
      sh[tid] += t;
      __syncthreads();
    }
    int incl = sh[tid];
    int c = carry;
    if (i < N_NODES) offsets[i] = c + incl - v;
    __syncthreads();
    if (tid == 0) carry = c + sh[1023];
    __syncthreads();
  }
  if (tid == 0) offsets[N_NODES] = carry;
}

__global__ __launch_bounds__(256) void scatter_kernel(
    const int* __restrict__ src, const int* __restrict__ dst,
    const int* __restrict__ offsets, int* __restrict__ fill,
    int* __restrict__ edst) {
  int i = blockIdx.x * 256 + threadIdx.x;
  if (i < E_TOT) {
    int s = src[i];
    int pos = offsets[s] + atomicAdd(&fill[s], 1);
    edst[pos] = dst[i];
  }
}

// one block per node: num/rowsum over its out-edges, elu, fused 512->1 matmul
__global__ __launch_bounds__(256) void aggregate_kernel(
    const __hip_bfloat16* __restrict__ h1, const float* __restrict__ f1,
    const float* __restrict__ f2, const int* __restrict__ offsets,
    const int* __restrict__ edst, const float* __restrict__ W_out,
    float* __restrict__ hout) {
  int n = blockIdx.x;
  int t = threadIdx.x;       // features 2t, 2t+1
  int head = t >> 5;
  int beg = offsets[n], end = offsets[n + 1];
  float f1v = f1[n * 8 + head];
  float acc0 = 0.f, acc1 = 0.f, rs = 0.f;
  for (int j = beg; j < end; ++j) {
    int d = edst[j];
    float s = f1v + f2[d * 8 + head];
    float lk = (s > 0.f) ? s : ALPHA * s;
    float e = expf(-lk);
    unsigned u = *reinterpret_cast<const unsigned*>(h1 + (size_t)d * FTOT + 2 * t);
    acc0 += e * bflo(u);
    acc1 += e * bfhi(u);
    rs += e;
  }
  float o0 = acc0 / rs, o1 = acc1 / rs;
  o0 = (o0 > 0.f) ? o0 : expm1f(o0);   // elu (concat=True path)
  o1 = (o1 > 0.f) ? o1 : expm1f(o1);
  float v = o0 * W_out[2 * t] + o1 * W_out[2 * t + 1];
#pragma unroll
  for (int o = 32; o > 0; o >>= 1) v += __shfl_down(v, o);
  __shared__ float red[4];
  if ((t & 63) == 0) red[t >> 6] = v;
  __syncthreads();
  if (t == 0) hout[n] = red[0] + red[1] + red[2] + red[3];
}

// layer-2 edge phase + elu + sigmoid. 4 nodes/block, one wave each.
__global__ __launch_bounds__(256) void layer2_kernel(
    const int* __restrict__ offsets, const int* __restrict__ edst,
    const float* __restrict__ hout, const float* __restrict__ a_out,
    float* __restrict__ out) {
  int n = blockIdx.x * 4 + (threadIdx.x >> 6);
  int l = threadIdx.x & 63;
  float a0 = a_out[0], a1 = a_out[1];
  int beg = offsets[n], end = offsets[n + 1];
  float f1v = hout[n] * a0;
  float rs = 0.f, num = 0.f;
  for (int j = beg + l; j < end; j += 64) {
    int d = edst[j];
    float hd = hout[d];
    float s = f1v + a1 * hd;
    float lk = (s > 0.f) ? s : ALPHA * s;
    float e = expf(-lk);
    rs += e;
    num += e * hd;
  }
#pragma unroll
  for (int o = 32; o > 0; o >>= 1) {
    rs += __shfl_down(rs, o);
    num += __shfl_down(num, o);
  }
  if (l == 0) {
    float o_ = num / rs;
    float el = (o_ > 0.f) ? o_ : expm1f(o_);
    out[n] = 1.f / (1.f + expf(-el));
  }
}

extern "C" void kernel_launch(void* const* d_in, const int* in_sizes, int n_in,
                              void* d_out, int out_size, void* d_ws, size_t ws_size,
                              hipStream_t stream) {
  const float* x = (const float*)d_in[0];
  const int* ei = (const int*)d_in[1];
  const float* W = (const float*)d_in[2];
  const float* a = (const float*)d_in[3];
  const float* W_out = (const float*)d_in[4];
  const float* a_out = (const float*)d_in[5];
  float* out = (float*)d_out;
  const int* src = ei;
  const int* dst = ei + E_TOT;

  char* p = (char*)d_ws;
  auto carve = [&](size_t bytes) {
    char* r = p;
    p += (bytes + 255) & ~(size_t)255;
    return r;
  };
  __hip_bfloat16* h1 = (__hip_bfloat16*)carve((size_t)N_NODES * FTOT * 2);
  float* f1 = (float*)carve((size_t)N_NODES * 8 * 4);
  float* f2 = (float*)carve((size_t)N_NODES * 8 * 4);
  int* offsets = (int*)carve((size_t)(N_NODES + 1) * 4);
  int* cnt = (int*)carve((size_t)N_NODES * 4);
  int* fill = (int*)carve((size_t)N_NODES * 4);
  int* edst = (int*)carve((size_t)E_TOT * 4);
  float* hout = (float*)carve((size_t)N_NODES * 4);

  hipMemsetAsync(cnt, 0, (size_t)N_NODES * 4, stream);
  hipMemsetAsync(fill, 0, (size_t)N_NODES * 4, stream);

  gemm_kernel<<<dim3(782, 8), 256, 0, stream>>>(x, W, h1);
  f1f2_kernel<<<12500, 256, 0, stream>>>(h1, a, f1, f2);
  hist_kernel<<<6446, 256, 0, stream>>>(src, cnt);
  scan_kernel<<<1, 1024, 0, stream>>>(cnt, offsets);
  scatter_kernel<<<6446, 256, 0, stream>>>(src, dst, offsets, fill, edst);
  aggregate_kernel<<<N_NODES, 256, 0, stream>>>(h1, f1, f2, offsets, edst, W_out, hout);
  layer2_kernel<<<12500, 256, 0, stream>>>(offsets, edst, hout, a_out, out);
}

// Round 2
// 727.872 us; speedup vs baseline: 1.2617x; 1.2617x over previous
//
#include <hip/hip_runtime.h>
#include <hip/hip_bf16.h>
#include <math.h>

#define N_NODES 50000
#define NFEAT 256
#define NHID 64
#define NHEADS 8
#define FTOT 512
#define E_TOT 1650000
#define ALPHA 0.2f

__device__ __forceinline__ float bflo(unsigned u) {
  union { unsigned u32; float f; } c; c.u32 = u << 16; return c.f;
}
__device__ __forceinline__ float bfhi(unsigned u) {
  union { unsigned u32; float f; } c; c.u32 = u & 0xffff0000u; return c.f;
}

// h1[n, head*64+j] = sum_k x[n,k] * W[head,k,j]   (fp32 accum, bf16 out)
// Fused epilogue: f1[n,head], f2[n,head] (the attention projections) computed
// from the fp32 accumulators via 16-lane shuffle reduction.
__global__ __launch_bounds__(256) void gemm_kernel(
    const float* __restrict__ x, const float* __restrict__ W,
    const float* __restrict__ a,
    __hip_bfloat16* __restrict__ h1, float* __restrict__ f1,
    float* __restrict__ f2) {
  __shared__ float As[16][65];   // [kk][m], padded vs 16-way store conflict
  __shared__ float Bs[16][64];   // [kk][c]
  int bm = blockIdx.x * 64;
  int head = blockIdx.y;
  const float* Wh = W + (size_t)head * NFEAT * NHID;
  int tid = threadIdx.x;
  int tr = tid >> 4, tc = tid & 15;
  float acc[4][4] = {};
  for (int k0 = 0; k0 < NFEAT; k0 += 16) {
#pragma unroll
    for (int i = 0; i < 4; ++i) {
      int idx = tid + i * 256;
      int r = idx >> 4, kk = idx & 15;
      int gr = bm + r;
      As[kk][r] = (gr < N_NODES) ? x[(size_t)gr * NFEAT + k0 + kk] : 0.f;
    }
#pragma unroll
    for (int i = 0; i < 4; ++i) {
      int idx = tid + i * 256;
      int kk = idx >> 6, c = idx & 63;
      Bs[kk][c] = Wh[(size_t)(k0 + kk) * NHID + c];
    }
    __syncthreads();
#pragma unroll
    for (int kk = 0; kk < 16; ++kk) {
      float av[4], bv[4];
#pragma unroll
      for (int i = 0; i < 4; ++i) av[i] = As[kk][tr * 4 + i];
#pragma unroll
      for (int j = 0; j < 4; ++j) bv[j] = Bs[kk][tc * 4 + j];
#pragma unroll
      for (int i = 0; i < 4; ++i)
#pragma unroll
        for (int j = 0; j < 4; ++j) acc[i][j] += av[i] * bv[j];
    }
    __syncthreads();
  }
  // store h1 (bf16)
#pragma unroll
  for (int i = 0; i < 4; ++i) {
    int row = bm + tr * 4 + i;
    if (row < N_NODES) {
      size_t base = (size_t)row * FTOT + head * 64 + tc * 4;
#pragma unroll
      for (int j = 0; j < 4; j += 2) {
        __hip_bfloat162 pr;
        pr.x = __float2bfloat16(acc[i][j]);
        pr.y = __float2bfloat16(acc[i][j + 1]);
        *reinterpret_cast<__hip_bfloat162*>(h1 + base + j) = pr;
      }
    }
  }
  // fused f1/f2: dot over the 64 cols of this head slice
  float a1v[4], a2v[4];
#pragma unroll
  for (int j = 0; j < 4; ++j) {
    a1v[j] = a[head * 128 + tc * 4 + j];
    a2v[j] = a[head * 128 + 64 + tc * 4 + j];
  }
#pragma unroll
  for (int i = 0; i < 4; ++i) {
    float p1 = 0.f, p2 = 0.f;
#pragma unroll
    for (int j = 0; j < 4; ++j) {
      p1 += acc[i][j] * a1v[j];
      p2 += acc[i][j] * a2v[j];
    }
#pragma unroll
    for (int o = 1; o < 16; o <<= 1) {
      p1 += __shfl_xor(p1, o);
      p2 += __shfl_xor(p2, o);
    }
    int row = bm + tr * 4 + i;
    if (tc == 0 && row < N_NODES) {
      f1[row * 8 + head] = p1;
      f2[row * 8 + head] = p2;
    }
  }
}

__global__ __launch_bounds__(256) void hist_kernel(const int* __restrict__ src,
                                                   int* __restrict__ cnt) {
  int i = blockIdx.x * 256 + threadIdx.x;
  if (i < E_TOT) atomicAdd(&cnt[src[i]], 1);
}

// exclusive prefix sum of cnt[50000] -> offsets[50001], single block of 1024
__global__ __launch_bounds__(1024) void scan_kernel(const int* __restrict__ cnt,
                                                    int* __restrict__ offsets) {
  __shared__ int sh[1024];
  __shared__ int carry;
  int tid = threadIdx.x;
  if (tid == 0) carry = 0;
  __syncthreads();
  for (int base = 0; base < N_NODES; base += 1024) {
    int i = base + tid;
    int v = (i < N_NODES) ? cnt[i] : 0;
    sh[tid] = v;
    __syncthreads();
    for (int off = 1; off < 1024; off <<= 1) {
      int t = (tid >= off) ? sh[tid - off] : 0;
      __syncthreads();
      sh[tid] += t;
      __syncthreads();
    }
    int incl = sh[tid];
    int c = carry;
    if (i < N_NODES) offsets[i] = c + incl - v;
    __syncthreads();
    if (tid == 0) carry = c + sh[1023];
    __syncthreads();
  }
  if (tid == 0) offsets[N_NODES] = carry;
}

__global__ __launch_bounds__(256) void scatter_kernel(
    const int* __restrict__ src, const int* __restrict__ dst,
    const int* __restrict__ offsets, int* __restrict__ fill,
    int* __restrict__ edst) {
  int i = blockIdx.x * 256 + threadIdx.x;
  if (i < E_TOT) {
    int s = src[i];
    int pos = offsets[s] + atomicAdd(&fill[s], 1);
    edst[pos] = dst[i];
  }
}

// one block per node; wave w handles edges beg+w, beg+w+4, ...
// lane l owns features [8l, 8l+8), head = l>>3. One dwordx4 per lane pulls
// the whole 1 KB h1 row per wave. 4 edges in flight per block.
__global__ __launch_bounds__(256) void aggregate_kernel(
    const __hip_bfloat16* __restrict__ h1, const float* __restrict__ f1,
    const float* __restrict__ f2, const int* __restrict__ offsets,
    const int* __restrict__ edst, const float* __restrict__ W_out,
    float* __restrict__ hout) {
  int n = blockIdx.x;
  int wv = threadIdx.x >> 6, l = threadIdx.x & 63;
  int head = l >> 3;
  int beg = offsets[n], end = offsets[n + 1];
  float f1v = f1[n * 8 + head];
  float acc[8] = {};
  float rs = 0.f;
  for (int j = beg + wv; j < end; j += 4) {
    int d = edst[j];
    float s = f1v + f2[d * 8 + head];
    float lk = (s > 0.f) ? s : ALPHA * s;
    float e = expf(-lk);
    rs += e;
    uint4 u = *reinterpret_cast<const uint4*>(h1 + (size_t)d * FTOT + l * 8);
    acc[0] += e * bflo(u.x); acc[1] += e * bfhi(u.x);
    acc[2] += e * bflo(u.y); acc[3] += e * bfhi(u.y);
    acc[4] += e * bflo(u.z); acc[5] += e * bfhi(u.z);
    acc[6] += e * bflo(u.w); acc[7] += e * bfhi(u.w);
  }
  __shared__ float sacc[4][FTOT];  // 8 KB
  __shared__ float srs[4][8];
#pragma unroll
  for (int k = 0; k < 8; ++k) sacc[wv][l * 8 + k] = acc[k];
  if ((l & 7) == 0) srs[wv][head] = rs;
  __syncthreads();
  // thread t finishes features 2t, 2t+1 and folds in the output-layer matmul
  int t = threadIdx.x;
  int hh = t >> 5;  // head of feature 2t
  float a0 = sacc[0][2 * t] + sacc[1][2 * t] + sacc[2][2 * t] + sacc[3][2 * t];
  float a1 = sacc[0][2 * t + 1] + sacc[1][2 * t + 1] + sacc[2][2 * t + 1] +
             sacc[3][2 * t + 1];
  float rsum = srs[0][hh] + srs[1][hh] + srs[2][hh] + srs[3][hh];
  float o0 = a0 / rsum, o1 = a1 / rsum;
  o0 = (o0 > 0.f) ? o0 : expm1f(o0);  // elu (concat=True path)
  o1 = (o1 > 0.f) ? o1 : expm1f(o1);
  float v = o0 * W_out[2 * t] + o1 * W_out[2 * t + 1];
#pragma unroll
  for (int o = 32; o > 0; o >>= 1) v += __shfl_down(v, o);
  __shared__ float red[4];
  if ((t & 63) == 0) red[t >> 6] = v;
  __syncthreads();
  if (t == 0) hout[n] = red[0] + red[1] + red[2] + red[3];
}

// layer-2 edge phase + elu + sigmoid. 4 nodes/block, one wave each.
__global__ __launch_bounds__(256) void layer2_kernel(
    const int* __restrict__ offsets, const int* __restrict__ edst,
    const float* __restrict__ hout, const float* __restrict__ a_out,
    float* __restrict__ out) {
  int n = blockIdx.x * 4 + (threadIdx.x >> 6);
  int l = threadIdx.x & 63;
  float a0 = a_out[0], a1 = a_out[1];
  int beg = offsets[n], end = offsets[n + 1];
  float f1v = hout[n] * a0;
  float rs = 0.f, num = 0.f;
  for (int j = beg + l; j < end; j += 64) {
    int d = edst[j];
    float hd = hout[d];
    float s = f1v + a1 * hd;
    float lk = (s > 0.f) ? s : ALPHA * s;
    float e = expf(-lk);
    rs += e;
    num += e * hd;
  }
#pragma unroll
  for (int o = 32; o > 0; o >>= 1) {
    rs += __shfl_down(rs, o);
    num += __shfl_down(num, o);
  }
  if (l == 0) {
    float o_ = num / rs;
    float el = (o_ > 0.f) ? o_ : expm1f(o_);
    out[n] = 1.f / (1.f + expf(-el));
  }
}

extern "C" void kernel_launch(void* const* d_in, const int* in_sizes, int n_in,
                              void* d_out, int out_size, void* d_ws, size_t ws_size,
                              hipStream_t stream) {
  const float* x = (const float*)d_in[0];
  const int* ei = (const int*)d_in[1];
  const float* W = (const float*)d_in[2];
  const float* a = (const float*)d_in[3];
  const float* W_out = (const float*)d_in[4];
  const float* a_out = (const float*)d_in[5];
  float* out = (float*)d_out;
  const int* src = ei;
  const int* dst = ei + E_TOT;

  char* p = (char*)d_ws;
  auto carve = [&](size_t bytes) {
    char* r = p;
    p += (bytes + 255) & ~(size_t)255;
    return r;
  };
  __hip_bfloat16* h1 = (__hip_bfloat16*)carve((size_t)N_NODES * FTOT * 2);
  float* f1 = (float*)carve((size_t)N_NODES * 8 * 4);
  float* f2 = (float*)carve((size_t)N_NODES * 8 * 4);
  int* offsets = (int*)carve((size_t)(N_NODES + 1) * 4);
  int* cnt = (int*)carve((size_t)N_NODES * 4);
  int* fill = (int*)carve((size_t)N_NODES * 4);
  int* edst = (int*)carve((size_t)E_TOT * 4);
  float* hout = (float*)carve((size_t)N_NODES * 4);

  hipMemsetAsync(cnt, 0, (size_t)N_NODES * 4, stream);
  hipMemsetAsync(fill, 0, (size_t)N_NODES * 4, stream);

  gemm_kernel<<<dim3(782, 8), 256, 0, stream>>>(x, W, a, h1, f1, f2);
  hist_kernel<<<6446, 256, 0, stream>>>(src, cnt);
  scan_kernel<<<1, 1024, 0, stream>>>(cnt, offsets);
  scatter_kernel<<<6446, 256, 0, stream>>>(src, dst, offsets, fill, edst);
  aggregate_kernel<<<N_NODES, 256, 0, stream>>>(h1, f1, f2, offsets, edst, W_out, hout);
  layer2_kernel<<<12500, 256, 0, stream>>>(offsets, edst, hout, a_out, out);
}

// Round 3
// 506.624 us; speedup vs baseline: 1.8127x; 1.4367x over previous
//
#include <hip/hip_runtime.h>
#include <hip/hip_bf16.h>
#include <hip/hip_fp16.h>
#include <math.h>

#define N_NODES 50000
#define NFEAT 256
#define NHID 64
#define NHEADS 8
#define FTOT 512
#define E_TOT 1650000
#define ALPHA 0.2f
#define NB_SCAN 196

typedef short s16x8 __attribute__((ext_vector_type(8)));
typedef float f32x4 __attribute__((ext_vector_type(4)));

__device__ __forceinline__ float bflo(unsigned u) {
  union { unsigned u32; float f; } c; c.u32 = u << 16; return c.f;
}
__device__ __forceinline__ float bfhi(unsigned u) {
  union { unsigned u32; float f; } c; c.u32 = u & 0xffff0000u; return c.f;
}
__device__ __forceinline__ short f2bf(float f) {  // RNE f32->bf16
  unsigned u = __float_as_uint(f);
  unsigned r = u + 0x7fffu + ((u >> 16) & 1u);
  return (short)(r >> 16);
}

// W[h][k][j] fp32 -> Wt[h][j][k] bf16 (transpose so GEMM B-frag k is contiguous)
__global__ __launch_bounds__(256) void wconv_kernel(const float* __restrict__ W,
                                                    short* __restrict__ Wt) {
  int idx = blockIdx.x * 256 + threadIdx.x;
  if (idx < NHEADS * NFEAT * NHID) {
    int h = idx >> 14, r = idx & 16383, k = r >> 6, j = r & 63;
    Wt[h * 16384 + j * 256 + k] = f2bf(W[idx]);
  }
}

// h1[64 rows x 512 cols] per block via bf16 MFMA. 8 waves, wave w = head w.
// Fused epilogue writes f1/f2.
__global__ __launch_bounds__(512) void gemm_mfma_kernel(
    const float* __restrict__ x, const short* __restrict__ Wt,
    const float* __restrict__ a, short* __restrict__ h1,
    float* __restrict__ f1, float* __restrict__ f2) {
  __shared__ __align__(16) short A_s[64 * 40];    // 40-short rows: uniform banks
  __shared__ __align__(16) short B_s[512 * 40];
  int bm = blockIdx.x * 64;
  int t = threadIdx.x;
  int wid = t >> 6, l = t & 63;
  int lr = l & 15, lk = l >> 4;
  f32x4 acc[4][4] = {};
  for (int k0 = 0; k0 < NFEAT; k0 += 32) {
    // stage A: 64x32 bf16 (convert from fp32 x)
    if (t < 256) {
      int row = t >> 2, c = t & 3;
      int gr = bm + row;
      s16x8 v = (s16x8)0;
      if (gr < N_NODES) {
        const float* src = x + (size_t)gr * NFEAT + k0 + c * 8;
        float4 p0 = *reinterpret_cast<const float4*>(src);
        float4 p1 = *reinterpret_cast<const float4*>(src + 4);
        v[0] = f2bf(p0.x); v[1] = f2bf(p0.y); v[2] = f2bf(p0.z); v[3] = f2bf(p0.w);
        v[4] = f2bf(p1.x); v[5] = f2bf(p1.y); v[6] = f2bf(p1.z); v[7] = f2bf(p1.w);
      }
      *reinterpret_cast<s16x8*>(&A_s[row * 40 + c * 8]) = v;
    }
    // stage B: 512 cols x 32 k from Wt (col-major-k contiguous)
    {
      const short* wsrc = Wt + (size_t)t * 256 + k0;
#pragma unroll
      for (int c = 0; c < 4; ++c) {
        *reinterpret_cast<s16x8*>(&B_s[t * 40 + c * 8]) =
            *reinterpret_cast<const s16x8*>(wsrc + c * 8);
      }
    }
    __syncthreads();
    s16x8 af[4], bf[4];
#pragma unroll
    for (int mi = 0; mi < 4; ++mi)
      af[mi] = *reinterpret_cast<const s16x8*>(&A_s[(mi * 16 + lr) * 40 + lk * 8]);
#pragma unroll
    for (int nj = 0; nj < 4; ++nj)
      bf[nj] = *reinterpret_cast<const s16x8*>(
          &B_s[(wid * 64 + nj * 16 + lr) * 40 + lk * 8]);
#pragma unroll
    for (int mi = 0; mi < 4; ++mi)
#pragma unroll
      for (int nj = 0; nj < 4; ++nj)
        acc[mi][nj] = __builtin_amdgcn_mfma_f32_16x16x32_bf16(
            af[mi], bf[nj], acc[mi][nj], 0, 0, 0);
    __syncthreads();
  }
  // store h1 (bf16 bits in short)
#pragma unroll
  for (int mi = 0; mi < 4; ++mi) {
#pragma unroll
    for (int nj = 0; nj < 4; ++nj) {
#pragma unroll
      for (int q = 0; q < 4; ++q) {
        int r = bm + mi * 16 + lk * 4 + q;
        if (r < N_NODES)
          h1[(size_t)r * FTOT + wid * 64 + nj * 16 + lr] = f2bf(acc[mi][nj][q]);
      }
    }
  }
  // fused f1/f2 for head=wid: dot over this wave's 64 cols
  float a1v[4], a2v[4];
#pragma unroll
  for (int nj = 0; nj < 4; ++nj) {
    a1v[nj] = a[wid * 128 + nj * 16 + lr];
    a2v[nj] = a[wid * 128 + 64 + nj * 16 + lr];
  }
#pragma unroll
  for (int mi = 0; mi < 4; ++mi) {
#pragma unroll
    for (int q = 0; q < 4; ++q) {
      float p1 = 0.f, p2 = 0.f;
#pragma unroll
      for (int nj = 0; nj < 4; ++nj) {
        p1 += acc[mi][nj][q] * a1v[nj];
        p2 += acc[mi][nj][q] * a2v[nj];
      }
      p1 += __shfl_xor(p1, 1); p2 += __shfl_xor(p2, 1);
      p1 += __shfl_xor(p1, 2); p2 += __shfl_xor(p2, 2);
      p1 += __shfl_xor(p1, 4); p2 += __shfl_xor(p2, 4);
      p1 += __shfl_xor(p1, 8); p2 += __shfl_xor(p2, 8);
      int r = bm + mi * 16 + lk * 4 + q;
      if (lr == 0 && r < N_NODES) {
        f1[r * 8 + wid] = p1;
        f2[r * 8 + wid] = p2;
      }
    }
  }
}

__global__ __launch_bounds__(256) void hist_kernel(const int* __restrict__ src,
                                                   int* __restrict__ cnt) {
  int i = blockIdx.x * 256 + threadIdx.x;
  if (i < E_TOT) atomicAdd(&cnt[src[i]], 1);
}

// hierarchical exclusive scan: per-block scan + block sums
__global__ __launch_bounds__(256) void scan1_kernel(const int* __restrict__ cnt,
                                                    int* __restrict__ offs,
                                                    int* __restrict__ bsum) {
  __shared__ int sh[256];
  int b = blockIdx.x, t = threadIdx.x, i = b * 256 + t;
  int v = (i < N_NODES) ? cnt[i] : 0;
  sh[t] = v;
  __syncthreads();
  for (int o = 1; o < 256; o <<= 1) {
    int u = (t >= o) ? sh[t - o] : 0;
    __syncthreads();
    sh[t] += u;
    __syncthreads();
  }
  if (i < N_NODES) offs[i] = sh[t] - v;
  if (t == 255) bsum[b] = sh[255];
}

__global__ __launch_bounds__(256) void scan2_kernel(int* __restrict__ bsum,
                                                    int* __restrict__ offs) {
  __shared__ int sh[256];
  int t = threadIdx.x;
  int v = (t < NB_SCAN) ? bsum[t] : 0;
  sh[t] = v;
  __syncthreads();
  for (int o = 1; o < 256; o <<= 1) {
    int u = (t >= o) ? sh[t - o] : 0;
    __syncthreads();
    sh[t] += u;
    __syncthreads();
  }
  if (t < NB_SCAN) bsum[t] = sh[t] - v;
  if (t == 255) offs[N_NODES] = sh[255];
}

__global__ __launch_bounds__(256) void scan3_kernel(int* __restrict__ offs,
                                                    const int* __restrict__ bsum) {
  int i = blockIdx.x * 256 + threadIdx.x;
  if (i < N_NODES) offs[i] += bsum[blockIdx.x];
}

__global__ __launch_bounds__(256) void scatter_kernel(
    const int* __restrict__ src, const int* __restrict__ dst,
    const int* __restrict__ offsets, int* __restrict__ fill,
    int* __restrict__ edst) {
  int i = blockIdx.x * 256 + threadIdx.x;
  if (i < E_TOT) {
    int s = src[i];
    int pos = offsets[s] + atomicAdd(&fill[s], 1);
    edst[pos] = dst[i];
  }
}

// per (edge,head): e = exp(-leakyrelu(f1[src]+f2[dst])), plus per-node rowsum.
// wave per node; 8 lanes per edge (lane&7 = head).
__global__ __launch_bounds__(256) void edge_e_kernel(
    const float* __restrict__ f1, const float* __restrict__ f2,
    const int* __restrict__ offsets, const int* __restrict__ edst,
    __half* __restrict__ eh, float* __restrict__ rowsum) {
  int wv = threadIdx.x >> 6, l = threadIdx.x & 63;
  int n = blockIdx.x * 4 + wv;
  int h = l & 7, sub = l >> 3;
  float f1v = f1[n * 8 + h];
  int beg = offsets[n], end = offsets[n + 1];
  float rs = 0.f;
  for (int j = beg + sub; j < end; j += 8) {
    int d = edst[j];
    float s = f1v + f2[d * 8 + h];
    float lk = (s > 0.f) ? s : ALPHA * s;
    float e = expf(-lk);
    eh[(size_t)j * 8 + h] = __float2half(e);
    rs += e;
  }
  rs += __shfl_xor(rs, 8);
  rs += __shfl_xor(rs, 16);
  rs += __shfl_xor(rs, 32);
  if (l < 8) rowsum[n * 8 + l] = rs;
}

// one block per node; wave w handles edges beg+w, beg+w+4, ...
// lane l owns features [8l, 8l+8), head = l>>3.
__global__ __launch_bounds__(256) void aggregate_kernel(
    const short* __restrict__ h1, const __half* __restrict__ eh,
    const float* __restrict__ rowsum, const int* __restrict__ offsets,
    const int* __restrict__ edst, const float* __restrict__ W_out,
    float* __restrict__ hout) {
  int n = blockIdx.x;
  int wv = threadIdx.x >> 6, l = threadIdx.x & 63;
  int head = l >> 3;
  int beg = offsets[n], end = offsets[n + 1];
  float acc[8] = {};
  for (int j = beg + wv; j < end; j += 4) {
    int d = edst[j];
    float e = __half2float(eh[(size_t)j * 8 + head]);
    uint4 u = *reinterpret_cast<const uint4*>(h1 + (size_t)d * FTOT + l * 8);
    acc[0] += e * bflo(u.x); acc[1] += e * bfhi(u.x);
    acc[2] += e * bflo(u.y); acc[3] += e * bfhi(u.y);
    acc[4] += e * bflo(u.z); acc[5] += e * bfhi(u.z);
    acc[6] += e * bflo(u.w); acc[7] += e * bfhi(u.w);
  }
  __shared__ float sacc[4][FTOT];  // 8 KB
#pragma unroll
  for (int k = 0; k < 8; ++k) sacc[wv][l * 8 + k] = acc[k];
  __syncthreads();
  int t = threadIdx.x;
  int hh = t >> 5;  // head of feature 2t
  float a0 = sacc[0][2 * t] + sacc[1][2 * t] + sacc[2][2 * t] + sacc[3][2 * t];
  float a1 = sacc[0][2 * t + 1] + sacc[1][2 * t + 1] + sacc[2][2 * t + 1] +
             sacc[3][2 * t + 1];
  float rsum = rowsum[n * 8 + hh];
  float o0 = a0 / rsum, o1 = a1 / rsum;
  o0 = (o0 > 0.f) ? o0 : expm1f(o0);  // elu (concat=True path)
  o1 = (o1 > 0.f) ? o1 : expm1f(o1);
  float v = o0 * W_out[2 * t] + o1 * W_out[2 * t + 1];
#pragma unroll
  for (int o = 32; o > 0; o >>= 1) v += __shfl_down(v, o);
  __shared__ float red[4];
  if ((t & 63) == 0) red[t >> 6] = v;
  __syncthreads();
  if (t == 0) hout[n] = red[0] + red[1] + red[2] + red[3];
}

// layer-2 edge phase + elu + sigmoid. 4 nodes/block, one wave each.
__global__ __launch_bounds__(256) void layer2_kernel(
    const int* __restrict__ offsets, const int* __restrict__ edst,
    const float* __restrict__ hout, const float* __restrict__ a_out,
    float* __restrict__ out) {
  int n = blockIdx.x * 4 + (threadIdx.x >> 6);
  int l = threadIdx.x & 63;
  float a0 = a_out[0], a1 = a_out[1];
  int beg = offsets[n], end = offsets[n + 1];
  float f1v = hout[n] * a0;
  float rs = 0.f, num = 0.f;
  for (int j = beg + l; j < end; j += 64) {
    int d = edst[j];
    float hd = hout[d];
    float s = f1v + a1 * hd;
    float lk = (s > 0.f) ? s : ALPHA * s;
    float e = expf(-lk);
    rs += e;
    num += e * hd;
  }
#pragma unroll
  for (int o = 32; o > 0; o >>= 1) {
    rs += __shfl_down(rs, o);
    num += __shfl_down(num, o);
  }
  if (l == 0) {
    float o_ = num / rs;
    float el = (o_ > 0.f) ? o_ : expm1f(o_);
    out[n] = 1.f / (1.f + expf(-el));
  }
}

extern "C" void kernel_launch(void* const* d_in, const int* in_sizes, int n_in,
                              void* d_out, int out_size, void* d_ws, size_t ws_size,
                              hipStream_t stream) {
  const float* x = (const float*)d_in[0];
  const int* ei = (const int*)d_in[1];
  const float* W = (const float*)d_in[2];
  const float* a = (const float*)d_in[3];
  const float* W_out = (const float*)d_in[4];
  const float* a_out = (const float*)d_in[5];
  float* out = (float*)d_out;
  const int* src = ei;
  const int* dst = ei + E_TOT;

  char* p = (char*)d_ws;
  auto carve = [&](size_t bytes) {
    char* r = p;
    p += (bytes + 255) & ~(size_t)255;
    return r;
  };
  short* h1 = (short*)carve((size_t)N_NODES * FTOT * 2);
  __half* eh = (__half*)carve((size_t)E_TOT * 8 * 2);
  float* f1 = (float*)carve((size_t)N_NODES * 8 * 4);
  float* f2 = (float*)carve((size_t)N_NODES * 8 * 4);
  float* rowsum = (float*)carve((size_t)N_NODES * 8 * 4);
  int* offsets = (int*)carve((size_t)(N_NODES + 1) * 4);
  int* cnt = (int*)carve((size_t)N_NODES * 4);
  int* fill = (int*)carve((size_t)N_NODES * 4);
  int* edst = (int*)carve((size_t)E_TOT * 4);
  int* bsum = (int*)carve((size_t)NB_SCAN * 4);
  short* Wt = (short*)carve((size_t)NHEADS * NFEAT * NHID * 2);
  float* hout = (float*)carve((size_t)N_NODES * 4);

  hipMemsetAsync(cnt, 0, (size_t)N_NODES * 4, stream);
  hipMemsetAsync(fill, 0, (size_t)N_NODES * 4, stream);

  wconv_kernel<<<512, 256, 0, stream>>>(W, Wt);
  gemm_mfma_kernel<<<782, 512, 0, stream>>>(x, Wt, a, h1, f1, f2);
  hist_kernel<<<6446, 256, 0, stream>>>(src, cnt);
  scan1_kernel<<<NB_SCAN, 256, 0, stream>>>(cnt, offsets, bsum);
  scan2_kernel<<<1, 256, 0, stream>>>(bsum, offsets);
  scan3_kernel<<<NB_SCAN, 256, 0, stream>>>(offsets, bsum);
  scatter_kernel<<<6446, 256, 0, stream>>>(src, dst, offsets, fill, edst);
  edge_e_kernel<<<12500, 256, 0, stream>>>(f1, f2, offsets, edst, eh, rowsum);
  aggregate_kernel<<<N_NODES, 256, 0, stream>>>(h1, eh, rowsum, offsets, edst, W_out, hout);
  layer2_kernel<<<12500, 256, 0, stream>>>(offsets, edst, hout, a_out, out);
}

// Round 4
// 464.117 us; speedup vs baseline: 1.9788x; 1.0916x over previous
//
#include <hip/hip_runtime.h>
#include <hip/hip_bf16.h>
#include <hip/hip_fp16.h>
#include <math.h>

#define N_NODES 50000
#define NFEAT 256
#define NHID 64
#define NHEADS 8
#define FTOT 512
#define E_TOT 1650000
#define ALPHA 0.2f
#define NB_SCAN 196

typedef short s16x8 __attribute__((ext_vector_type(8)));
typedef float f32x4 __attribute__((ext_vector_type(4)));

__device__ __forceinline__ short f2bf(float f) {  // RNE f32->bf16
  unsigned u = __float_as_uint(f);
  unsigned r = u + 0x7fffu + ((u >> 16) & 1u);
  return (short)(r >> 16);
}

__device__ __forceinline__ float att_e(float f1v, float g) {
  float s = f1v + g;
  float lk = (s > 0.f) ? s : ALPHA * s;
  return expf(-lk);
}

__device__ __forceinline__ void fma8(float e, const uint4& u, float* acc) {
  const __half2* hp = reinterpret_cast<const __half2*>(&u);
#pragma unroll
  for (int k = 0; k < 4; ++k) {
    float2 f = __half22float2(hp[k]);
    acc[2 * k] += e * f.x;
    acc[2 * k + 1] += e * f.y;
  }
}

// W[h][k][j] fp32 -> Wt[h][j][k] bf16 (transpose so GEMM B-frag k is contiguous)
__global__ __launch_bounds__(256) void wconv_kernel(const float* __restrict__ W,
                                                    short* __restrict__ Wt) {
  int idx = blockIdx.x * 256 + threadIdx.x;
  if (idx < NHEADS * NFEAT * NHID) {
    int h = idx >> 14, r = idx & 16383, k = r >> 6, j = r & 63;
    Wt[h * 16384 + j * 256 + k] = f2bf(W[idx]);
  }
}

// h1[64 rows x 512 cols] per block via bf16 MFMA. 8 waves, wave w = head w.
// Fused epilogue writes f1/f2 (fp32) and h1 (fp16).
__global__ __launch_bounds__(512) void gemm_mfma_kernel(
    const float* __restrict__ x, const short* __restrict__ Wt,
    const float* __restrict__ a, __half* __restrict__ h1,
    float* __restrict__ f1, float* __restrict__ f2) {
  __shared__ __align__(16) short A_s[64 * 40];    // 40-short rows: uniform banks
  __shared__ __align__(16) short B_s[512 * 40];
  int bm = blockIdx.x * 64;
  int t = threadIdx.x;
  int wid = t >> 6, l = t & 63;
  int lr = l & 15, lk = l >> 4;
  f32x4 acc[4][4] = {};
  for (int k0 = 0; k0 < NFEAT; k0 += 32) {
    if (t < 256) {
      int row = t >> 2, c = t & 3;
      int gr = bm + row;
      s16x8 v = (s16x8)0;
      if (gr < N_NODES) {
        const float* src = x + (size_t)gr * NFEAT + k0 + c * 8;
        float4 p0 = *reinterpret_cast<const float4*>(src);
        float4 p1 = *reinterpret_cast<const float4*>(src + 4);
        v[0] = f2bf(p0.x); v[1] = f2bf(p0.y); v[2] = f2bf(p0.z); v[3] = f2bf(p0.w);
        v[4] = f2bf(p1.x); v[5] = f2bf(p1.y); v[6] = f2bf(p1.z); v[7] = f2bf(p1.w);
      }
      *reinterpret_cast<s16x8*>(&A_s[row * 40 + c * 8]) = v;
    }
    {
      const short* wsrc = Wt + (size_t)t * 256 + k0;
#pragma unroll
      for (int c = 0; c < 4; ++c) {
        *reinterpret_cast<s16x8*>(&B_s[t * 40 + c * 8]) =
            *reinterpret_cast<const s16x8*>(wsrc + c * 8);
      }
    }
    __syncthreads();
    s16x8 af[4], bf[4];
#pragma unroll
    for (int mi = 0; mi < 4; ++mi)
      af[mi] = *reinterpret_cast<const s16x8*>(&A_s[(mi * 16 + lr) * 40 + lk * 8]);
#pragma unroll
    for (int nj = 0; nj < 4; ++nj)
      bf[nj] = *reinterpret_cast<const s16x8*>(
          &B_s[(wid * 64 + nj * 16 + lr) * 40 + lk * 8]);
#pragma unroll
    for (int mi = 0; mi < 4; ++mi)
#pragma unroll
      for (int nj = 0; nj < 4; ++nj)
        acc[mi][nj] = __builtin_amdgcn_mfma_f32_16x16x32_bf16(
            af[mi], bf[nj], acc[mi][nj], 0, 0, 0);
    __syncthreads();
  }
  // store h1 (fp16)
#pragma unroll
  for (int mi = 0; mi < 4; ++mi) {
#pragma unroll
    for (int nj = 0; nj < 4; ++nj) {
#pragma unroll
      for (int q = 0; q < 4; ++q) {
        int r = bm + mi * 16 + lk * 4 + q;
        if (r < N_NODES)
          h1[(size_t)r * FTOT + wid * 64 + nj * 16 + lr] =
              __float2half(acc[mi][nj][q]);
      }
    }
  }
  // fused f1/f2 for head=wid
  float a1v[4], a2v[4];
#pragma unroll
  for (int nj = 0; nj < 4; ++nj) {
    a1v[nj] = a[wid * 128 + nj * 16 + lr];
    a2v[nj] = a[wid * 128 + 64 + nj * 16 + lr];
  }
#pragma unroll
  for (int mi = 0; mi < 4; ++mi) {
#pragma unroll
    for (int q = 0; q < 4; ++q) {
      float p1 = 0.f, p2 = 0.f;
#pragma unroll
      for (int nj = 0; nj < 4; ++nj) {
        p1 += acc[mi][nj][q] * a1v[nj];
        p2 += acc[mi][nj][q] * a2v[nj];
      }
      p1 += __shfl_xor(p1, 1); p2 += __shfl_xor(p2, 1);
      p1 += __shfl_xor(p1, 2); p2 += __shfl_xor(p2, 2);
      p1 += __shfl_xor(p1, 4); p2 += __shfl_xor(p2, 4);
      p1 += __shfl_xor(p1, 8); p2 += __shfl_xor(p2, 8);
      int r = bm + mi * 16 + lk * 4 + q;
      if (lr == 0 && r < N_NODES) {
        f1[r * 8 + wid] = p1;
        f2[r * 8 + wid] = p2;
      }
    }
  }
}

__global__ __launch_bounds__(256) void hist_kernel(const int* __restrict__ src,
                                                   int* __restrict__ cnt) {
  int i = blockIdx.x * 256 + threadIdx.x;
  if (i < E_TOT) atomicAdd(&cnt[src[i]], 1);
}

__global__ __launch_bounds__(256) void scan1_kernel(const int* __restrict__ cnt,
                                                    int* __restrict__ offs,
                                                    int* __restrict__ bsum) {
  __shared__ int sh[256];
  int b = blockIdx.x, t = threadIdx.x, i = b * 256 + t;
  int v = (i < N_NODES) ? cnt[i] : 0;
  sh[t] = v;
  __syncthreads();
  for (int o = 1; o < 256; o <<= 1) {
    int u = (t >= o) ? sh[t - o] : 0;
    __syncthreads();
    sh[t] += u;
    __syncthreads();
  }
  if (i < N_NODES) offs[i] = sh[t] - v;
  if (t == 255) bsum[b] = sh[255];
}

__global__ __launch_bounds__(256) void scan2_kernel(int* __restrict__ bsum,
                                                    int* __restrict__ offs) {
  __shared__ int sh[256];
  int t = threadIdx.x;
  int v = (t < NB_SCAN) ? bsum[t] : 0;
  sh[t] = v;
  __syncthreads();
  for (int o = 1; o < 256; o <<= 1) {
    int u = (t >= o) ? sh[t - o] : 0;
    __syncthreads();
    sh[t] += u;
    __syncthreads();
  }
  if (t < NB_SCAN) bsum[t] = sh[t] - v;
  if (t == 255) offs[N_NODES] = sh[255];
}

__global__ __launch_bounds__(256) void scan3_kernel(int* __restrict__ offs,
                                                    const int* __restrict__ bsum) {
  int i = blockIdx.x * 256 + threadIdx.x;
  if (i < N_NODES) offs[i] += bsum[blockIdx.x];
}

__global__ __launch_bounds__(256) void scatter_kernel(
    const int* __restrict__ src, const int* __restrict__ dst,
    const int* __restrict__ offsets, int* __restrict__ fill,
    int* __restrict__ edst) {
  int i = blockIdx.x * 256 + threadIdx.x;
  if (i < E_TOT) {
    int s = src[i];
    int pos = offsets[s] + atomicAdd(&fill[s], 1);
    edst[pos] = dst[i];
  }
}

// one block per node; wave w handles edges beg+w, beg+w+4, ...
// lane l owns features [8l, 8l+8), head = l>>3. Fused e-computation;
// 4-deep explicit gather pipeline (the latency fix: VGPRs up from 16).
__global__ __launch_bounds__(256) void aggregate_kernel(
    const __half* __restrict__ h1, const float* __restrict__ f1,
    const float* __restrict__ f2, const int* __restrict__ offsets,
    const int* __restrict__ edst, const float* __restrict__ W_out,
    float* __restrict__ hout) {
  int n = blockIdx.x;
  int wv = threadIdx.x >> 6, l = threadIdx.x & 63;
  int head = l >> 3;
  int beg = offsets[n], end = offsets[n + 1];
  float f1v = f1[n * 8 + head];
  float acc[8] = {};
  float rs = 0.f;
  int j = beg + wv;
  for (; j + 12 < end; j += 16) {
    int d0 = edst[j], d1 = edst[j + 4], d2 = edst[j + 8], d3 = edst[j + 12];
    uint4 u0 = *reinterpret_cast<const uint4*>(h1 + (size_t)d0 * FTOT + l * 8);
    uint4 u1 = *reinterpret_cast<const uint4*>(h1 + (size_t)d1 * FTOT + l * 8);
    uint4 u2 = *reinterpret_cast<const uint4*>(h1 + (size_t)d2 * FTOT + l * 8);
    uint4 u3 = *reinterpret_cast<const uint4*>(h1 + (size_t)d3 * FTOT + l * 8);
    float g0 = f2[d0 * 8 + head];
    float g1 = f2[d1 * 8 + head];
    float g2 = f2[d2 * 8 + head];
    float g3 = f2[d3 * 8 + head];
    float e0 = att_e(f1v, g0), e1 = att_e(f1v, g1);
    float e2 = att_e(f1v, g2), e3 = att_e(f1v, g3);
    rs += (e0 + e1) + (e2 + e3);
    fma8(e0, u0, acc);
    fma8(e1, u1, acc);
    fma8(e2, u2, acc);
    fma8(e3, u3, acc);
  }
  for (; j < end; j += 4) {
    int d = edst[j];
    uint4 u = *reinterpret_cast<const uint4*>(h1 + (size_t)d * FTOT + l * 8);
    float e = att_e(f1v, f2[d * 8 + head]);
    rs += e;
    fma8(e, u, acc);
  }
  __shared__ float sacc[4][FTOT];  // 8 KB
  __shared__ float srs[4][8];
#pragma unroll
  for (int k = 0; k < 8; ++k) sacc[wv][l * 8 + k] = acc[k];
  if ((l & 7) == 0) srs[wv][head] = rs;
  __syncthreads();
  int t = threadIdx.x;
  int hh = t >> 5;  // head of feature 2t
  float a0 = sacc[0][2 * t] + sacc[1][2 * t] + sacc[2][2 * t] + sacc[3][2 * t];
  float a1 = sacc[0][2 * t + 1] + sacc[1][2 * t + 1] + sacc[2][2 * t + 1] +
             sacc[3][2 * t + 1];
  float rsum = srs[0][hh] + srs[1][hh] + srs[2][hh] + srs[3][hh];
  float o0 = a0 / rsum, o1 = a1 / rsum;
  o0 = (o0 > 0.f) ? o0 : expm1f(o0);  // elu (concat=True path)
  o1 = (o1 > 0.f) ? o1 : expm1f(o1);
  float v = o0 * W_out[2 * t] + o1 * W_out[2 * t + 1];
#pragma unroll
  for (int o = 32; o > 0; o >>= 1) v += __shfl_down(v, o);
  __shared__ float red[4];
  if ((t & 63) == 0) red[t >> 6] = v;
  __syncthreads();
  if (t == 0) hout[n] = red[0] + red[1] + red[2] + red[3];
}

// layer-2 edge phase + elu + sigmoid. 4 nodes/block, one wave each.
__global__ __launch_bounds__(256) void layer2_kernel(
    const int* __restrict__ offsets, const int* __restrict__ edst,
    const float* __restrict__ hout, const float* __restrict__ a_out,
    float* __restrict__ out) {
  int n = blockIdx.x * 4 + (threadIdx.x >> 6);
  int l = threadIdx.x & 63;
  float a0 = a_out[0], a1 = a_out[1];
  int beg = offsets[n], end = offsets[n + 1];
  float f1v = hout[n] * a0;
  float rs = 0.f, num = 0.f;
  for (int j = beg + l; j < end; j += 64) {
    int d = edst[j];
    float hd = hout[d];
    float s = f1v + a1 * hd;
    float lk = (s > 0.f) ? s : ALPHA * s;
    float e = expf(-lk);
    rs += e;
    num += e * hd;
  }
#pragma unroll
  for (int o = 32; o > 0; o >>= 1) {
    rs += __shfl_down(rs, o);
    num += __shfl_down(num, o);
  }
  if (l == 0) {
    float o_ = num / rs;
    float el = (o_ > 0.f) ? o_ : expm1f(o_);
    out[n] = 1.f / (1.f + expf(-el));
  }
}

extern "C" void kernel_launch(void* const* d_in, const int* in_sizes, int n_in,
                              void* d_out, int out_size, void* d_ws, size_t ws_size,
                              hipStream_t stream) {
  const float* x = (const float*)d_in[0];
  const int* ei = (const int*)d_in[1];
  const float* W = (const float*)d_in[2];
  const float* a = (const float*)d_in[3];
  const float* W_out = (const float*)d_in[4];
  const float* a_out = (const float*)d_in[5];
  float* out = (float*)d_out;
  const int* src = ei;
  const int* dst = ei + E_TOT;

  char* p = (char*)d_ws;
  auto carve = [&](size_t bytes) {
    char* r = p;
    p += (bytes + 255) & ~(size_t)255;
    return r;
  };
  __half* h1 = (__half*)carve((size_t)N_NODES * FTOT * 2);
  float* f1 = (float*)carve((size_t)N_NODES * 8 * 4);
  float* f2 = (float*)carve((size_t)N_NODES * 8 * 4);
  int* offsets = (int*)carve((size_t)(N_NODES + 1) * 4);
  int* cnt = (int*)carve((size_t)N_NODES * 4);
  int* fill = (int*)carve((size_t)N_NODES * 4);
  int* edst = (int*)carve((size_t)E_TOT * 4);
  int* bsum = (int*)carve((size_t)NB_SCAN * 4);
  short* Wt = (short*)carve((size_t)NHEADS * NFEAT * NHID * 2);
  float* hout = (float*)carve((size_t)N_NODES * 4);

  hipMemsetAsync(cnt, 0, (size_t)N_NODES * 4, stream);
  hipMemsetAsync(fill, 0, (size_t)N_NODES * 4, stream);

  wconv_kernel<<<512, 256, 0, stream>>>(W, Wt);
  gemm_mfma_kernel<<<782, 512, 0, stream>>>(x, Wt, a, h1, f1, f2);
  hist_kernel<<<6446, 256, 0, stream>>>(src, cnt);
  scan1_kernel<<<NB_SCAN, 256, 0, stream>>>(cnt, offsets, bsum);
  scan2_kernel<<<1, 256, 0, stream>>>(bsum, offsets);
  scan3_kernel<<<NB_SCAN, 256, 0, stream>>>(offsets, bsum);
  scatter_kernel<<<6446, 256, 0, stream>>>(src, dst, offsets, fill, edst);
  aggregate_kernel<<<N_NODES, 256, 0, stream>>>(h1, f1, f2, offsets, edst, W_out, hout);
  layer2_kernel<<<12500, 256, 0, stream>>>(offsets, edst, hout, a_out, out);
}